// Round 1
// baseline (729.483 us; speedup 1.0000x reference)
//
#include <hip/hip_runtime.h>
#include <hip/hip_bf16.h>
#include <math.h>

#define S_LEN 256
#define B_SZ  512
#define D_DIM 1024
#define CAND_ 1024

// ---------------------------------------------------------------------------
// Kernel 1: x_ = x @ W^T + bias   (B x CAND) @ (D x CAND)^T -> (B x D), f32
// Tiled LDS GEMM: 32(b) x 64(d) tile, K-step 32, 256 threads, 2x4 per thread.
// ---------------------------------------------------------------------------
#define TB 32
#define TD 64
#define TK 32

__launch_bounds__(256, 2)
__global__ void transform_gemm(const float* __restrict__ x,
                               const float* __restrict__ W,
                               const float* __restrict__ bias,
                               float* __restrict__ xw) {
    __shared__ float xt[TK][TB + 2];   // [k][b], pad 2 (float2-aligned reads)
    __shared__ float wt[TK][TD + 4];   // [k][d], pad 4 (float4-aligned reads)

    const int b0 = blockIdx.x * TB;
    const int d0 = blockIdx.y * TD;
    const int t  = threadIdx.x;
    const int td = t & 15;             // 0..15 -> 4 d's
    const int tb = t >> 4;             // 0..15 -> 2 b's

    float acc0[4] = {0.f, 0.f, 0.f, 0.f};
    float acc1[4] = {0.f, 0.f, 0.f, 0.f};

    const int xr  = t >> 3;            // 0..31
    const int xkc = t & 7;             // 0..7

    for (int k0 = 0; k0 < CAND_; k0 += TK) {
        // stage x tile (TB x TK), transposed to [k][b]
        {
            float4 xv = *(const float4*)&x[(size_t)(b0 + xr) * CAND_ + k0 + xkc * 4];
            xt[xkc * 4 + 0][xr] = xv.x;
            xt[xkc * 4 + 1][xr] = xv.y;
            xt[xkc * 4 + 2][xr] = xv.z;
            xt[xkc * 4 + 3][xr] = xv.w;
        }
        // stage W tile (TD x TK), transposed to [k][d]
        #pragma unroll
        for (int h = 0; h < 2; ++h) {
            int c   = t + h * 256;
            int wr  = c >> 3;          // 0..63
            int wkc = c & 7;           // 0..7
            float4 wv = *(const float4*)&W[(size_t)(d0 + wr) * CAND_ + k0 + wkc * 4];
            wt[wkc * 4 + 0][wr] = wv.x;
            wt[wkc * 4 + 1][wr] = wv.y;
            wt[wkc * 4 + 2][wr] = wv.z;
            wt[wkc * 4 + 3][wr] = wv.w;
        }
        __syncthreads();
        #pragma unroll
        for (int k = 0; k < TK; ++k) {
            float2 xa = *(const float2*)&xt[k][tb * 2];
            float4 wv = *(const float4*)&wt[k][td * 4];
            acc0[0] = fmaf(xa.x, wv.x, acc0[0]);
            acc0[1] = fmaf(xa.x, wv.y, acc0[1]);
            acc0[2] = fmaf(xa.x, wv.z, acc0[2]);
            acc0[3] = fmaf(xa.x, wv.w, acc0[3]);
            acc1[0] = fmaf(xa.y, wv.x, acc1[0]);
            acc1[1] = fmaf(xa.y, wv.y, acc1[1]);
            acc1[2] = fmaf(xa.y, wv.z, acc1[2]);
            acc1[3] = fmaf(xa.y, wv.w, acc1[3]);
        }
        __syncthreads();
    }

    const float4 bv = *(const float4*)&bias[d0 + td * 4];
    const int b = b0 + tb * 2;
    const int d = d0 + td * 4;
    float4 o0 = {acc0[0] + bv.x, acc0[1] + bv.y, acc0[2] + bv.z, acc0[3] + bv.w};
    float4 o1 = {acc1[0] + bv.x, acc1[1] + bv.y, acc1[2] + bv.z, acc1[3] + bv.w};
    *(float4*)&xw[(size_t)b * D_DIM + d]       = o0;
    *(float4*)&xw[(size_t)(b + 1) * D_DIM + d] = o1;
}

// ---------------------------------------------------------------------------
// Kernel 2: fused scores + tanh + masked-softmax + renorm + pooling.
// One block per batch b (512 threads = 8 waves). Each wave owns 32 s-rows:
//   row = M[s,b,:] (4 KB) loaded as 4x float4/lane; score via wave butterfly
//   reduce (no barriers in loop); w = mask*exp(tanh(score*mask^2));
//   acc += w*row in registers. One LDS combine at the end.
// Single pass over M: 512 MiB total HBM read.
// ---------------------------------------------------------------------------
#define NW 8
#define NS (S_LEN / NW)

__launch_bounds__(512, 2)
__global__ void fused_attn(const float* __restrict__ M,
                           const float* __restrict__ mask,
                           const float* __restrict__ xw,
                           float* __restrict__ out) {
    __shared__ float s_acc[NW][D_DIM];   // 32 KB
    __shared__ float s_w[S_LEN];
    __shared__ float s_den[NW];

    const int b    = blockIdx.x;
    const int tid  = threadIdx.x;
    const int lane = tid & 63;
    const int wv   = tid >> 6;

    // x_[b] fragment: lane holds d = 4*lane + 256*j, j=0..3
    const float4* xp = (const float4*)(xw + (size_t)b * D_DIM);
    const float4 x0 = xp[lane];
    const float4 x1 = xp[lane + 64];
    const float4 x2 = xp[lane + 128];
    const float4 x3 = xp[lane + 192];

    const float* mrow = mask + (size_t)b * S_LEN;

    float4 a0 = {0, 0, 0, 0}, a1 = {0, 0, 0, 0}, a2 = {0, 0, 0, 0}, a3 = {0, 0, 0, 0};
    float denom = 0.f;

    const int s_begin = wv * NS;
    const float4* rp = (const float4*)(M + ((size_t)s_begin * B_SZ + b) * D_DIM);
    float4 c0 = rp[lane];
    float4 c1 = rp[lane + 64];
    float4 c2 = rp[lane + 128];
    float4 c3 = rp[lane + 192];

    for (int i = 0; i < NS; ++i) {
        const int s = s_begin + i;
        // prefetch next row (uniform branch; skipped only on last iter)
        float4 n0 = c0, n1 = c1, n2 = c2, n3 = c3;
        if (i + 1 < NS) {
            const float4* np = (const float4*)(M + ((size_t)(s + 1) * B_SZ + b) * D_DIM);
            n0 = np[lane];
            n1 = np[lane + 64];
            n2 = np[lane + 128];
            n3 = np[lane + 192];
        }
        // partial dot
        float p = c0.x * x0.x;
        p = fmaf(c0.y, x0.y, p); p = fmaf(c0.z, x0.z, p); p = fmaf(c0.w, x0.w, p);
        p = fmaf(c1.x, x1.x, p); p = fmaf(c1.y, x1.y, p); p = fmaf(c1.z, x1.z, p);
        p = fmaf(c1.w, x1.w, p); p = fmaf(c2.x, x2.x, p); p = fmaf(c2.y, x2.y, p);
        p = fmaf(c2.z, x2.z, p); p = fmaf(c2.w, x2.w, p); p = fmaf(c3.x, x3.x, p);
        p = fmaf(c3.y, x3.y, p); p = fmaf(c3.z, x3.z, p); p = fmaf(c3.w, x3.w, p);
        // wave-64 butterfly reduce: all lanes get the full dot
        #pragma unroll
        for (int off = 32; off > 0; off >>= 1)
            p += __shfl_xor(p, off, 64);

        const float mk    = mrow[s];
        const float score = p * mk * mk;   // reference applies mask to M and to scores
        const float w     = mk * expf(tanhf(score));
        denom += w;
        if (lane == 0) s_w[s] = w;

        a0.x = fmaf(w, c0.x, a0.x); a0.y = fmaf(w, c0.y, a0.y);
        a0.z = fmaf(w, c0.z, a0.z); a0.w = fmaf(w, c0.w, a0.w);
        a1.x = fmaf(w, c1.x, a1.x); a1.y = fmaf(w, c1.y, a1.y);
        a1.z = fmaf(w, c1.z, a1.z); a1.w = fmaf(w, c1.w, a1.w);
        a2.x = fmaf(w, c2.x, a2.x); a2.y = fmaf(w, c2.y, a2.y);
        a2.z = fmaf(w, c2.z, a2.z); a2.w = fmaf(w, c2.w, a2.w);
        a3.x = fmaf(w, c3.x, a3.x); a3.y = fmaf(w, c3.y, a3.y);
        a3.z = fmaf(w, c3.z, a3.z); a3.w = fmaf(w, c3.w, a3.w);

        c0 = n0; c1 = n1; c2 = n2; c3 = n3;
    }

    // combine across waves
    float* sa = &s_acc[wv][0];
    ((float4*)sa)[lane]       = a0;
    ((float4*)sa)[lane + 64]  = a1;
    ((float4*)sa)[lane + 128] = a2;
    ((float4*)sa)[lane + 192] = a3;
    if (lane == 0) s_den[wv] = denom;
    __syncthreads();

    float dtot = 0.f;
    #pragma unroll
    for (int w8 = 0; w8 < NW; ++w8) dtot += s_den[w8];
    const float inv = 1.0f / dtot;

    // attn_pool: 1024 d over 512 threads -> 2 each
    #pragma unroll
    for (int j = 0; j < 2; ++j) {
        const int d = tid * 2 + j;
        float v = 0.f;
        #pragma unroll
        for (int w8 = 0; w8 < NW; ++w8) v += s_acc[w8][d];
        out[(size_t)b * D_DIM + d] = v * inv;
    }
    // alpha: (B,1,S) after attn_pool (B,D)
    if (tid < S_LEN) {
        out[(size_t)B_SZ * D_DIM + (size_t)b * S_LEN + tid] = s_w[tid] * inv;
    }
}

extern "C" void kernel_launch(void* const* d_in, const int* in_sizes, int n_in,
                              void* d_out, int out_size, void* d_ws, size_t ws_size,
                              hipStream_t stream) {
    const float* M    = (const float*)d_in[0];   // (S, B, D)
    const float* x    = (const float*)d_in[1];   // (B, CAND)
    const float* mask = (const float*)d_in[2];   // (B, S)
    const float* W    = (const float*)d_in[3];   // (D, CAND)
    const float* bias = (const float*)d_in[4];   // (D,)
    float* out = (float*)d_out;

    // scratch for x_ (B x D f32 = 2 MiB); fall back to the attn_pool region of
    // d_out (block b reads only x_[b] before writing pool[b] -> no hazard).
    const size_t xw_bytes = (size_t)B_SZ * D_DIM * sizeof(float);
    float* xw = (ws_size >= xw_bytes) ? (float*)d_ws : out;

    dim3 ggrid(B_SZ / TB, D_DIM / TD);
    transform_gemm<<<ggrid, 256, 0, stream>>>(x, W, bias, xw);
    fused_attn<<<B_SZ, 512, 0, stream>>>(M, mask, xw, out);
}